// Round 1
// baseline (2114.721 us; speedup 1.0000x reference)
//
#include <hip/hip_runtime.h>
#include <hip/hip_bf16.h>

// Problem constants (validated against in_sizes at runtime where cheap).
// N=200000, E=3200000, R=8, B=2, IN=128, H=32, OUT=128, U=10000, T=50000.

// ---------------------------------------------------------------------------
// Basis projection + self-loop kernel.
// Computes hb[n,b,o] = sum_i h[n,i] * V[b,i,o]   (b=0,1; o=0..31)
// and      agg[n,o]  = sum_i h[n,i] * loop[i,o] + bias[o]
// CW in LDS holds [DIN][96]: cols 0..63 = V bases, 64..95 = loop weights.
template<int DIN>
__global__ __launch_bounds__(192)
void k_hb(const float* __restrict__ h, const float* __restrict__ V,
          const float* __restrict__ loopw, const float* __restrict__ bias,
          float* __restrict__ hb, float* __restrict__ agg, int nNodes)
{
    __shared__ float CW[DIN * 96];
    for (int idx = threadIdx.x; idx < DIN * 96; idx += 192) {
        int i = idx / 96, c = idx % 96;
        CW[idx] = (c < 64) ? V[(c >> 5) * DIN * 32 + i * 32 + (c & 31)]
                           : loopw[i * 32 + (c - 64)];
    }
    __syncthreads();
    const int c = threadIdx.x % 96;       // output column 0..95
    const int local = threadIdx.x / 96;   // 0 or 1 -> node within pair
    const float bv = (c >= 64) ? bias[c - 64] : 0.f;
    for (int n = blockIdx.x * 2 + local; n < nNodes; n += gridDim.x * 2) {
        const float* hr = h + (long)n * DIN;
        float acc = 0.f;
        #pragma unroll 8
        for (int i = 0; i < DIN; ++i) acc = fmaf(hr[i], CW[i * 96 + c], acc);
        if (c < 64) hb[(long)n * 64 + c] = acc;
        else        agg[(long)n * 32 + (c - 64)] = acc + bv;
    }
}

// ---------------------------------------------------------------------------
// Edge message + scatter-add. One thread per (edge, out-feature).
// msg = comb[etype,0]*hb[src,0,o] + comb[etype,1]*hb[src,1,o]
__global__ __launch_bounds__(256)
void k_msg(const int* __restrict__ src, const int* __restrict__ dst,
           const int* __restrict__ et, const float* __restrict__ comb,
           const float* __restrict__ hb, float* __restrict__ agg, int nEdges)
{
    int gid = blockIdx.x * 256 + threadIdx.x;
    int e = gid >> 5;
    if (e >= nEdges) return;
    int o = gid & 31;
    int s = src[e], d = dst[e], r = et[e];
    float c0 = comb[2 * r], c1 = comb[2 * r + 1];
    const float* hp = hb + (long)s * 64;
    float v = fmaf(c0, hp[o], c1 * hp[32 + o]);
    atomicAdd(agg + (long)d * 32 + o, v);
}

// ---------------------------------------------------------------------------
__global__ __launch_bounds__(256)
void k_tanh(float* __restrict__ p, int n)
{
    int i = blockIdx.x * 256 + threadIdx.x;
    if (i < n) p[i] = tanhf(p[i]);
}

// ---------------------------------------------------------------------------
// Fused MLP heads + reparameterization.
// cs = [h0|h1|h2] (96). hidden = relu(cs@W1+b1) (32). out = hidden@W2+b2 (128).
// z = mean + noise * exp(log_std). One 32-thread group per node, 8 nodes/block.
__global__ __launch_bounds__(256)
void k_mlp(const float* __restrict__ h0, const float* __restrict__ h1,
           const float* __restrict__ h2,
           const float* __restrict__ Wm1, const float* __restrict__ bm1,
           const float* __restrict__ Wm2, const float* __restrict__ bm2,
           const float* __restrict__ Ws1, const float* __restrict__ bs1,
           const float* __restrict__ Ws2, const float* __restrict__ bs2,
           const float* __restrict__ noise, float* __restrict__ z, int nNodes)
{
    __shared__ float sW1[2][96 * 32];
    __shared__ float sW2[2][32 * 128];
    __shared__ float sb1[2][32];
    __shared__ float sb2[2][128];
    __shared__ float shid[2][256];
    for (int i = threadIdx.x; i < 96 * 32; i += 256) { sW1[0][i] = Wm1[i]; sW1[1][i] = Ws1[i]; }
    for (int i = threadIdx.x; i < 32 * 128; i += 256) { sW2[0][i] = Wm2[i]; sW2[1][i] = Ws2[i]; }
    if (threadIdx.x < 32)  { sb1[0][threadIdx.x] = bm1[threadIdx.x]; sb1[1][threadIdx.x] = bs1[threadIdx.x]; }
    if (threadIdx.x < 128) { sb2[0][threadIdx.x] = bm2[threadIdx.x]; sb2[1][threadIdx.x] = bs2[threadIdx.x]; }
    __syncthreads();
    const int g = threadIdx.x >> 5;   // group (node slot) 0..7
    const int j = threadIdx.x & 31;   // hidden index
    for (int base = blockIdx.x * 8; base < nNodes; base += gridDim.x * 8) {
        int n = base + g;
        float hm = 0.f, hs = 0.f;
        if (n < nNodes) {
            const float* p0 = h0 + (long)n * 32;
            const float* p1 = h1 + (long)n * 32;
            const float* p2 = h2 + (long)n * 32;
            #pragma unroll 4
            for (int k = 0; k < 32; ++k) {
                float c = p0[k];
                hm = fmaf(c, sW1[0][k * 32 + j], hm);
                hs = fmaf(c, sW1[1][k * 32 + j], hs);
            }
            #pragma unroll 4
            for (int k = 0; k < 32; ++k) {
                float c = p1[k];
                hm = fmaf(c, sW1[0][(32 + k) * 32 + j], hm);
                hs = fmaf(c, sW1[1][(32 + k) * 32 + j], hs);
            }
            #pragma unroll 4
            for (int k = 0; k < 32; ++k) {
                float c = p2[k];
                hm = fmaf(c, sW1[0][(64 + k) * 32 + j], hm);
                hs = fmaf(c, sW1[1][(64 + k) * 32 + j], hs);
            }
        }
        hm = fmaxf(hm + sb1[0][j], 0.f);   // relu(cs@Wm1+bm1)
        hs = fmaxf(hs + sb1[1][j], 0.f);   // relu(cs@Ws1+bs1)
        __syncthreads();                   // protect shid reuse (prev iter reads done)
        shid[0][threadIdx.x] = hm;
        shid[1][threadIdx.x] = hs;
        __syncthreads();
        if (n < nNodes) {
            float am[4] = {0.f, 0.f, 0.f, 0.f};
            float as_[4] = {0.f, 0.f, 0.f, 0.f};
            for (int k = 0; k < 32; ++k) {
                float vm = shid[0][g * 32 + k];
                float vs = shid[1][g * 32 + k];
                #pragma unroll
                for (int q = 0; q < 4; ++q) {
                    am[q]  = fmaf(vm, sW2[0][k * 128 + q * 32 + j], am[q]);
                    as_[q] = fmaf(vs, sW2[1][k * 128 + q * 32 + j], as_[q]);
                }
            }
            #pragma unroll
            for (int q = 0; q < 4; ++q) {
                int o = q * 32 + j;
                float mean = am[q] + sb2[0][o];
                float ls   = as_[q] + sb2[1][o];
                z[(long)n * 128 + o] = fmaf(noise[(long)n * 128 + o], expf(ls), mean);
            }
        }
    }
}

// ---------------------------------------------------------------------------
// One wave per (user,item) pair: write both z rows into `results` and the dot
// into xs. out layout: [xs (U)] [preds (T)] [results (2U x 128)].
__global__ __launch_bounds__(256)
void k_pairs(const float* __restrict__ z, const int* __restrict__ ui,
             const int* __restrict__ ii, float* __restrict__ out, int U, int T)
{
    int w = (blockIdx.x * 256 + threadIdx.x) >> 6;
    int lane = threadIdx.x & 63;
    if (w >= U) return;
    int a = ui[w], b = ii[w];
    float a0 = z[(long)a * 128 + lane], a1 = z[(long)a * 128 + 64 + lane];
    float b0 = z[(long)b * 128 + lane], b1 = z[(long)b * 128 + 64 + lane];
    float* res = out + U + T;
    res[(long)w * 128 + lane] = a0;
    res[(long)w * 128 + 64 + lane] = a1;
    res[(long)(U + w) * 128 + lane] = b0;
    res[(long)(U + w) * 128 + 64 + lane] = b1;
    float d = fmaf(a0, b0, a1 * b1);
    #pragma unroll
    for (int off = 32; off; off >>= 1) d += __shfl_xor(d, off);
    if (lane == 0) out[w] = d;
}

// One wave per test edge: dot(z[te_src], z[te_dst]) -> preds.
__global__ __launch_bounds__(256)
void k_preds(const float* __restrict__ z, const int* __restrict__ ts,
             const int* __restrict__ td, float* __restrict__ out, int U, int T)
{
    int w = (blockIdx.x * 256 + threadIdx.x) >> 6;
    int lane = threadIdx.x & 63;
    if (w >= T) return;
    int a = ts[w], b = td[w];
    float a0 = z[(long)a * 128 + lane], a1 = z[(long)a * 128 + 64 + lane];
    float b0 = z[(long)b * 128 + lane], b1 = z[(long)b * 128 + 64 + lane];
    float d = fmaf(a0, b0, a1 * b1);
    #pragma unroll
    for (int off = 32; off; off >>= 1) d += __shfl_xor(d, off);
    if (lane == 0) out[U + w] = d;
}

// ---------------------------------------------------------------------------
extern "C" void kernel_launch(void* const* d_in, const int* in_sizes, int n_in,
                              void* d_out, int out_size, void* d_ws, size_t ws_size,
                              hipStream_t stream)
{
    const float* x     = (const float*)d_in[0];
    const int*   src   = (const int*)d_in[1];
    const int*   dst   = (const int*)d_in[2];
    const int*   et    = (const int*)d_in[3];
    const float* noise = (const float*)d_in[4];
    const int*   ui    = (const int*)d_in[5];
    const int*   ii    = (const int*)d_in[6];
    const int*   tes   = (const int*)d_in[7];
    const int*   ted   = (const int*)d_in[8];
    const float* V0    = (const float*)d_in[9];
    const float* comb0 = (const float*)d_in[10];
    const float* loop0 = (const float*)d_in[11];
    const float* b0    = (const float*)d_in[12];
    const float* V1    = (const float*)d_in[13];
    const float* comb1 = (const float*)d_in[14];
    const float* loop1 = (const float*)d_in[15];
    const float* b1    = (const float*)d_in[16];
    const float* V2    = (const float*)d_in[17];
    const float* comb2 = (const float*)d_in[18];
    const float* loop2 = (const float*)d_in[19];
    const float* b2    = (const float*)d_in[20];
    const float* Wm1   = (const float*)d_in[21];
    const float* bm1   = (const float*)d_in[22];
    const float* Wm2   = (const float*)d_in[23];
    const float* bm2   = (const float*)d_in[24];
    const float* Ws1   = (const float*)d_in[25];
    const float* bs1   = (const float*)d_in[26];
    const float* Ws2   = (const float*)d_in[27];
    const float* bs2   = (const float*)d_in[28];

    const int N = in_sizes[0] / 128;   // 200000
    const int E = in_sizes[1];         // 3200000
    const int U = in_sizes[5];         // 10000
    const int T = in_sizes[7];         // 50000

    float* out = (float*)d_out;

    // Workspace layout (floats): hb[N*64] | h0[N*32] | h1[N*32] | h2[N*32] | z[N*128]
    float* ws = (float*)d_ws;
    float* hb = ws;
    float* h0 = hb + (long)N * 64;
    float* h1 = h0 + (long)N * 32;
    float* h2 = h1 + (long)N * 32;
    float* z  = h2 + (long)N * 32;     // total 57.6M floats = 230.4 MB

    const int msgBlocks = (E * 32 + 255) / 256;
    const int ewBlocks  = (N * 32 + 255) / 256;

    // ---- layer 0 (din=128) ----
    k_hb<128><<<4096, 192, 0, stream>>>(x, V0, loop0, b0, hb, h0, N);
    k_msg<<<msgBlocks, 256, 0, stream>>>(src, dst, et, comb0, hb, h0, E);
    k_tanh<<<ewBlocks, 256, 0, stream>>>(h0, N * 32);
    // ---- layer 1 (din=32) ----
    k_hb<32><<<4096, 192, 0, stream>>>(h0, V1, loop1, b1, hb, h1, N);
    k_msg<<<msgBlocks, 256, 0, stream>>>(src, dst, et, comb1, hb, h1, E);
    k_tanh<<<ewBlocks, 256, 0, stream>>>(h1, N * 32);
    // ---- layer 2 (din=32) ----
    k_hb<32><<<4096, 192, 0, stream>>>(h1, V2, loop2, b2, hb, h2, N);
    k_msg<<<msgBlocks, 256, 0, stream>>>(src, dst, et, comb2, hb, h2, E);
    k_tanh<<<ewBlocks, 256, 0, stream>>>(h2, N * 32);
    // ---- heads + reparameterization ----
    k_mlp<<<2500, 256, 0, stream>>>(h0, h1, h2, Wm1, bm1, Wm2, bm2,
                                    Ws1, bs1, Ws2, bs2, noise, z, N);
    // ---- outputs ----
    k_pairs<<<(U * 64 + 255) / 256, 256, 0, stream>>>(z, ui, ii, out, U, T);
    k_preds<<<(T * 64 + 255) / 256, 256, 0, stream>>>(z, tes, ted, out, U, T);
}